// Round 4
// baseline (951.210 us; speedup 1.0000x reference)
//
#include <hip/hip_runtime.h>
#include <math.h>

#define N_NODES 100000
#define N_EDGES 1600000
#define D 128
#define NCLASS 10
#define NLAYERS 3
#define BN_EPS 1e-5f

#define LDA 136        // padded LDS row stride in bf16 elems
#define BUCKET_SH 7    // 128 nodes per bucket
#define NBUK 782       // ceil(100000/128)
#define NBLK 128       // partition blocks
#define CHUNK 12500    // N_EDGES / NBLK (exact)
#define NSCAN (NBUK * NBLK)      // 100096 = 391*256
#define SCAN_BLKS 391

typedef __attribute__((ext_vector_type(8))) short bf16x8;
typedef __attribute__((ext_vector_type(4))) float f32x4;

__device__ __forceinline__ ushort f2b(float x) {          // RNE fp32 -> bf16
    uint u = __float_as_uint(x);
    return (ushort)((u + 0x7fffu + ((u >> 16) & 1u)) >> 16);
}
__device__ __forceinline__ float b2f(uint u) {            // bf16 bits -> fp32 (exact)
    return __uint_as_float(u << 16);
}
__device__ __forceinline__ uint pack2(float a, float b) {
    return (uint)f2b(a) | ((uint)f2b(b) << 16);
}

// ================= CSR build: radix partition, no global atomics =================
// A: per-block histogram over buckets -> hist[buk*NBLK + blk]
__global__ __launch_bounds__(256) void k_hist(const int* __restrict__ dst,
                                              int* __restrict__ hist) {
    __shared__ int lh[NBUK];
    int t = threadIdx.x, b = blockIdx.x;
    for (int i = t; i < NBUK; i += 256) lh[i] = 0;
    __syncthreads();
    int e0 = b * CHUNK;
    for (int e = e0 + t; e < e0 + CHUNK; e += 256)
        atomicAdd(&lh[dst[e] >> BUCKET_SH], 1);
    __syncthreads();
    for (int i = t; i < NBUK; i += 256) hist[i * NBLK + b] = lh[i];
}

// B1: per-256-chunk exclusive scan (in place), chunk totals -> psums
__global__ __launch_bounds__(256) void k_scan1(int* __restrict__ hist, int* __restrict__ psums) {
    __shared__ int sh[256];
    int t = threadIdx.x;
    int i = blockIdx.x * 256 + t;
    int v = hist[i];
    sh[t] = v; __syncthreads();
    for (int off = 1; off < 256; off <<= 1) {
        int a = (t >= off) ? sh[t - off] : 0;
        __syncthreads();
        sh[t] += a;
        __syncthreads();
    }
    hist[i] = sh[t] - v;
    if (t == 255) psums[blockIdx.x] = sh[255];
}

// B2: exclusive scan of the 391 chunk totals
__global__ __launch_bounds__(512) void k_scan2(int* __restrict__ psums) {
    __shared__ int sh[512];
    int t = threadIdx.x;
    int v = (t < SCAN_BLKS) ? psums[t] : 0;
    sh[t] = v; __syncthreads();
    for (int off = 1; off < 512; off <<= 1) {
        int a = (t >= off) ? sh[t - off] : 0;
        __syncthreads();
        sh[t] += a;
        __syncthreads();
    }
    if (t < SCAN_BLKS) psums[t] = sh[t] - v;
}

// B3: add chunk base
__global__ __launch_bounds__(256) void k_scan3(int* __restrict__ hist, const int* __restrict__ psums) {
    hist[blockIdx.x * 256 + threadIdx.x] += psums[blockIdx.x];
}

// C: planned scatter via LDS cursors (packed src | d_local<<17)
__global__ __launch_bounds__(256) void k_partition(const int* __restrict__ src,
                                                   const int* __restrict__ dst,
                                                   const int* __restrict__ off,
                                                   uint* __restrict__ tmp) {
    __shared__ int lcur[NBUK];
    int t = threadIdx.x, b = blockIdx.x;
    for (int i = t; i < NBUK; i += 256) lcur[i] = off[i * NBLK + b];
    __syncthreads();
    int e0 = b * CHUNK;
    for (int e = e0 + t; e < e0 + CHUNK; e += 256) {
        int d = dst[e];
        int bk = d >> BUCKET_SH;
        int pos = atomicAdd(&lcur[bk], 1);
        tmp[pos] = (uint)src[e] | ((uint)(d & ((1 << BUCKET_SH) - 1)) << 17);
    }
}

// D: per-bucket LDS histogram + scan -> row_ptr + csr fill (LDS cursors only)
__global__ __launch_bounds__(256) void k_bucket_fill(const uint* __restrict__ tmp,
                                                     const int* __restrict__ off,
                                                     int* __restrict__ row_ptr,
                                                     int* __restrict__ csr) {
    __shared__ int hist[128], inc[128], cur[128];
    int b = blockIdx.x, t = threadIdx.x;
    int base = off[b * NBLK];
    int end  = (b + 1 < NBUK) ? off[(b + 1) * NBLK] : N_EDGES;
    int nb = end - base;
    int lo = b << BUCKET_SH;
    const uint* bt = tmp + base;

    if (t < 128) hist[t] = 0;
    __syncthreads();
    for (int i = t; i < nb; i += 256)
        atomicAdd(&hist[bt[i] >> 17], 1);
    __syncthreads();
    if (t < 128) inc[t] = hist[t];
    __syncthreads();
    for (int offs = 1; offs < 128; offs <<= 1) {
        int a = (t < 128 && t >= offs) ? inc[t - offs] : 0;
        __syncthreads();
        if (t < 128) inc[t] += a;
        __syncthreads();
    }
    if (t < 128) {
        int node = lo + t;
        if (node < N_NODES) row_ptr[node] = base + inc[t] - hist[t];
        cur[t] = 0;
    }
    if (b == NBUK - 1 && t == 0) row_ptr[N_NODES] = base + nb;
    __syncthreads();
    for (int i = t; i < nb; i += 256) {
        uint u = bt[i];
        int dl = u >> 17;
        int s = (int)(u & 0x1ffffu);
        int p = atomicAdd(&cur[dl], 1);
        csr[base + (inc[dl] - hist[dl]) + p] = s;
    }
}

// ================= fp32 -> bf16 bulk convert =================
__global__ void k_tobf16(const float* __restrict__ x, ushort* __restrict__ o) {
    int i = blockIdx.x * 256 + threadIdx.x;
    const int n4 = N_NODES * D / 4;
    if (i < n4) {
        float4 v = ((const float4*)x)[i];
        uint2 u;
        u.x = pack2(v.x, v.y);
        u.y = pack2(v.z, v.w);
        ((uint2*)o)[i] = u;
    }
}

// ================= fused aggregate + GEMM1 + BN stats =================
// block = one 128-node bucket. Gathers (h + sum neighbors) into sA (bf16),
// then z = sA @ W.T + bias (MFMA), writes z bf16, fused column sum/sumsq.
__global__ __launch_bounds__(256, 2) void k_agg_gemm(const ushort* __restrict__ hbf,
                                                     const int* __restrict__ row_ptr,
                                                     const int* __restrict__ csr,
                                                     const float* __restrict__ W,
                                                     const float* __restrict__ bias,
                                                     ushort* __restrict__ zout,
                                                     float* __restrict__ gsum,
                                                     float* __restrict__ gsq) {
    __shared__ ushort sA[128 * LDA];
    __shared__ ushort sB[128 * LDA];
    __shared__ float sbias[128];

    int t = threadIdx.x;
    int r0 = blockIdx.x << BUCKET_SH;
    int lane = t & 63, wid = t >> 6;

    // stage W [f][k] fp32 -> bf16 LDS
    for (int idx = t; idx < 128 * 32; idx += 256) {
        int f = idx >> 5, c4 = (idx & 31) << 2;
        float4 v = *(const float4*)(W + f * 128 + c4);
        ushort4 u;
        u.x = f2b(v.x); u.y = f2b(v.y); u.z = f2b(v.z); u.w = f2b(v.w);
        *(ushort4*)&sB[f * LDA + c4] = u;
    }
    if (t < 128) sbias[t] = bias[t];

    // gather phase: each wave handles nodes n = wid, wid+4, ... (32 nodes)
    const uint* hp = (const uint*)hbf;
    for (int n = wid; n < 128; n += 4) {
        int r = r0 + n;
        uint* dstw = (uint*)&sA[n * LDA];
        if (r < N_NODES) {
            uint self = hp[(size_t)r * 64 + lane];
            float ax = b2f(self & 0xffffu), ay = b2f(self >> 16);
            int e0 = row_ptr[r], e1 = row_ptr[r + 1];
            int e = e0;
            for (; e + 7 < e1; e += 8) {
                uint v0 = hp[(size_t)csr[e]     * 64 + lane];
                uint v1 = hp[(size_t)csr[e + 1] * 64 + lane];
                uint v2 = hp[(size_t)csr[e + 2] * 64 + lane];
                uint v3 = hp[(size_t)csr[e + 3] * 64 + lane];
                uint v4 = hp[(size_t)csr[e + 4] * 64 + lane];
                uint v5 = hp[(size_t)csr[e + 5] * 64 + lane];
                uint v6 = hp[(size_t)csr[e + 6] * 64 + lane];
                uint v7 = hp[(size_t)csr[e + 7] * 64 + lane];
                ax += b2f(v0 & 0xffffu); ay += b2f(v0 >> 16);
                ax += b2f(v1 & 0xffffu); ay += b2f(v1 >> 16);
                ax += b2f(v2 & 0xffffu); ay += b2f(v2 >> 16);
                ax += b2f(v3 & 0xffffu); ay += b2f(v3 >> 16);
                ax += b2f(v4 & 0xffffu); ay += b2f(v4 >> 16);
                ax += b2f(v5 & 0xffffu); ay += b2f(v5 >> 16);
                ax += b2f(v6 & 0xffffu); ay += b2f(v6 >> 16);
                ax += b2f(v7 & 0xffffu); ay += b2f(v7 >> 16);
            }
            for (; e < e1; ++e) {
                uint v = hp[(size_t)csr[e] * 64 + lane];
                ax += b2f(v & 0xffffu); ay += b2f(v >> 16);
            }
            dstw[lane] = pack2(ax, ay);
        } else {
            dstw[lane] = 0u;
        }
    }
    __syncthreads();

    int rl = lane & 15, g = lane >> 4;
    int wr = wid >> 1, wc = wid & 1;

    f32x4 acc[4][4];
#pragma unroll
    for (int i = 0; i < 4; ++i)
#pragma unroll
        for (int j = 0; j < 4; ++j) acc[i][j] = (f32x4){0.f, 0.f, 0.f, 0.f};

#pragma unroll
    for (int ks = 0; ks < 4; ++ks) {
        int koff = ks * 32 + g * 8;
        bf16x8 a[4], b[4];
#pragma unroll
        for (int mi = 0; mi < 4; ++mi)
            a[mi] = *(const bf16x8*)&sA[(wr * 64 + mi * 16 + rl) * LDA + koff];
#pragma unroll
        for (int ni = 0; ni < 4; ++ni)
            b[ni] = *(const bf16x8*)&sB[(wc * 64 + ni * 16 + rl) * LDA + koff];
#pragma unroll
        for (int mi = 0; mi < 4; ++mi)
#pragma unroll
            for (int ni = 0; ni < 4; ++ni)
                acc[mi][ni] = __builtin_amdgcn_mfma_f32_16x16x32_bf16(a[mi], b[ni], acc[mi][ni], 0, 0, 0);
    }

    float bn[4], ssum[4], ssq[4];
#pragma unroll
    for (int ni = 0; ni < 4; ++ni) {
        bn[ni] = sbias[wc * 64 + ni * 16 + rl];
        ssum[ni] = 0.f; ssq[ni] = 0.f;
    }

#pragma unroll
    for (int mi = 0; mi < 4; ++mi) {
        int orow = r0 + wr * 64 + mi * 16 + g * 4;
#pragma unroll
        for (int j = 0; j < 4; ++j) {
            int row = orow + j;
            if (row < N_NODES) {
#pragma unroll
                for (int ni = 0; ni < 4; ++ni) {
                    int ocol = wc * 64 + ni * 16 + rl;
                    float o = acc[mi][ni][j] + bn[ni];
                    ssum[ni] += o; ssq[ni] += o * o;
                    zout[(size_t)row * 128 + ocol] = f2b(o);
                }
            }
        }
    }

#pragma unroll
    for (int ni = 0; ni < 4; ++ni) {
        float s = ssum[ni], q = ssq[ni];
        s += __shfl_xor(s, 16, 64); q += __shfl_xor(q, 16, 64);
        s += __shfl_xor(s, 32, 64); q += __shfl_xor(q, 32, 64);
        if (g == 0) {
            int col = wc * 64 + ni * 16 + rl;
            atomicAdd(&gsum[col], s);
            atomicAdd(&gsq[col], q);
        }
    }
}

// ================= MFMA GEMM (no stats) =================
// PRE: 0 = copy bf16 A; 2 = relu(a*scale[k]+shift[k]).  POST: 1 = relu.  bf16 out.
template <int PRE, int POST>
__global__ __launch_bounds__(256, 2) void k_gemm(const ushort* __restrict__ inA,
                                                 const float* __restrict__ W,
                                                 const float* __restrict__ bias,
                                                 const float* __restrict__ scale,
                                                 const float* __restrict__ shift,
                                                 ushort* __restrict__ outp,
                                                 int nrows) {
    __shared__ ushort sA[128 * LDA];
    __shared__ ushort sB[128 * LDA];
    __shared__ float sbias[128];

    int t = threadIdx.x;
    int r0 = blockIdx.x * 128;

    for (int idx = t; idx < 128 * 32; idx += 256) {
        int f = idx >> 5, c4 = (idx & 31) << 2;
        float4 v = *(const float4*)(W + f * 128 + c4);
        ushort4 u;
        u.x = f2b(v.x); u.y = f2b(v.y); u.z = f2b(v.z); u.w = f2b(v.w);
        *(ushort4*)&sB[f * LDA + c4] = u;
    }
    if (t < 128) sbias[t] = bias[t];

    for (int idx = t; idx < 128 * 16; idx += 256) {
        int r = idx >> 4, c8 = (idx & 15) << 3;
        int rr = r0 + r;
        uint4 v = make_uint4(0u, 0u, 0u, 0u);
        if (rr < nrows) v = *(const uint4*)(inA + (size_t)rr * 128 + c8);
        if (PRE == 2) {
            float f0 = b2f(v.x & 0xffffu), f1 = b2f(v.x >> 16);
            float f2 = b2f(v.y & 0xffffu), f3 = b2f(v.y >> 16);
            float f4 = b2f(v.z & 0xffffu), f5 = b2f(v.z >> 16);
            float f6 = b2f(v.w & 0xffffu), f7 = b2f(v.w >> 16);
            float4 sc0 = *(const float4*)(scale + c8);
            float4 sc1 = *(const float4*)(scale + c8 + 4);
            float4 sf0 = *(const float4*)(shift + c8);
            float4 sf1 = *(const float4*)(shift + c8 + 4);
            f0 = fmaxf(fmaf(f0, sc0.x, sf0.x), 0.f);
            f1 = fmaxf(fmaf(f1, sc0.y, sf0.y), 0.f);
            f2 = fmaxf(fmaf(f2, sc0.z, sf0.z), 0.f);
            f3 = fmaxf(fmaf(f3, sc0.w, sf0.w), 0.f);
            f4 = fmaxf(fmaf(f4, sc1.x, sf1.x), 0.f);
            f5 = fmaxf(fmaf(f5, sc1.y, sf1.y), 0.f);
            f6 = fmaxf(fmaf(f6, sc1.z, sf1.z), 0.f);
            f7 = fmaxf(fmaf(f7, sc1.w, sf1.w), 0.f);
            v.x = pack2(f0, f1); v.y = pack2(f2, f3);
            v.z = pack2(f4, f5); v.w = pack2(f6, f7);
        }
        *(uint4*)&sA[r * LDA + c8] = v;
    }
    __syncthreads();

    int lane = t & 63, wid = t >> 6;
    int rl = lane & 15, g = lane >> 4;
    int wr = wid >> 1, wc = wid & 1;

    f32x4 acc[4][4];
#pragma unroll
    for (int i = 0; i < 4; ++i)
#pragma unroll
        for (int j = 0; j < 4; ++j) acc[i][j] = (f32x4){0.f, 0.f, 0.f, 0.f};

#pragma unroll
    for (int ks = 0; ks < 4; ++ks) {
        int koff = ks * 32 + g * 8;
        bf16x8 a[4], b[4];
#pragma unroll
        for (int mi = 0; mi < 4; ++mi)
            a[mi] = *(const bf16x8*)&sA[(wr * 64 + mi * 16 + rl) * LDA + koff];
#pragma unroll
        for (int ni = 0; ni < 4; ++ni)
            b[ni] = *(const bf16x8*)&sB[(wc * 64 + ni * 16 + rl) * LDA + koff];
#pragma unroll
        for (int mi = 0; mi < 4; ++mi)
#pragma unroll
            for (int ni = 0; ni < 4; ++ni)
                acc[mi][ni] = __builtin_amdgcn_mfma_f32_16x16x32_bf16(a[mi], b[ni], acc[mi][ni], 0, 0, 0);
    }

    float bn[4];
#pragma unroll
    for (int ni = 0; ni < 4; ++ni) bn[ni] = sbias[wc * 64 + ni * 16 + rl];

#pragma unroll
    for (int mi = 0; mi < 4; ++mi) {
        int orow = r0 + wr * 64 + mi * 16 + g * 4;
#pragma unroll
        for (int j = 0; j < 4; ++j) {
            int row = orow + j;
            if (row < nrows) {
#pragma unroll
                for (int ni = 0; ni < 4; ++ni) {
                    int ocol = wc * 64 + ni * 16 + rl;
                    float o = acc[mi][ni][j] + bn[ni];
                    if (POST) o = fmaxf(o, 0.f);
                    outp[(size_t)row * 128 + ocol] = f2b(o);
                }
            }
        }
    }
}

// ================= BN finalize =================
__global__ void k_bnfin(const float* __restrict__ gsum, const float* __restrict__ gsq,
                        const float* __restrict__ gamma, const float* __restrict__ beta,
                        float* __restrict__ scale, float* __restrict__ shift) {
    int d = threadIdx.x;
    float mu = gsum[d] * (1.f / N_NODES);
    float var = gsq[d] * (1.f / N_NODES) - mu * mu;
    float rstd = rsqrtf(var + BN_EPS);
    float sc = rstd * gamma[d];
    scale[d] = sc;
    shift[d] = beta[d] - mu * sc;
}

// ================= head: out = sigmoid(tin @ lin2_W.T + lin2_b) =================
__global__ __launch_bounds__(128) void k_head2(const ushort* __restrict__ tin,
                                               const float* __restrict__ W2,
                                               const float* __restrict__ b2,
                                               float* __restrict__ out) {
    __shared__ float sh[128 * 130];
    __shared__ float w2s[NCLASS * 128];
    __shared__ float b2s[NCLASS];
    int t = threadIdx.x;
    int r0 = blockIdx.x * 128;

    for (int idx = t; idx < (NCLASS * 128) / 4; idx += 128) {
        float4 v = *(const float4*)(W2 + idx * 4);
        *(float4*)&w2s[idx * 4] = v;
    }
    if (t < NCLASS) b2s[t] = b2[t];

    const uint* tp = (const uint*)tin;
    for (int idx = t; idx < 128 * 64; idx += 128) {
        int r = idx >> 6, c2 = idx & 63;
        int rr = r0 + r;
        uint v = (rr < N_NODES) ? tp[(size_t)rr * 64 + c2] : 0u;
        sh[r * 130 + 2 * c2]     = b2f(v & 0xffffu);
        sh[r * 130 + 2 * c2 + 1] = b2f(v >> 16);
    }
    __syncthreads();

    float acc[NCLASS];
#pragma unroll
    for (int c = 0; c < NCLASS; ++c) acc[c] = 0.f;
    const float* myrow = &sh[t * 130];
#pragma unroll 4
    for (int k = 0; k < 128; ++k) {
        float v = myrow[k];
#pragma unroll
        for (int c = 0; c < NCLASS; ++c)
            acc[c] = fmaf(v, w2s[c * 128 + k], acc[c]);
    }
    int rr = r0 + t;
    if (rr < N_NODES) {
#pragma unroll
        for (int c = 0; c < NCLASS; ++c) {
            float z = acc[c] + b2s[c];
            out[(size_t)rr * NCLASS + c] = 1.f / (1.f + expf(-z));
        }
    }
}

// ================= launcher =================
extern "C" void kernel_launch(void* const* d_in, const int* in_sizes, int n_in,
                              void* d_out, int out_size, void* d_ws, size_t ws_size,
                              hipStream_t stream) {
    const float* x     = (const float*)d_in[0];
    const int*   ei    = (const int*)d_in[1];
    const float* W1    = (const float*)d_in[2];
    const float* b1    = (const float*)d_in[3];
    const float* gamma = (const float*)d_in[4];
    const float* beta  = (const float*)d_in[5];
    const float* W2    = (const float*)d_in[6];
    const float* b2    = (const float*)d_in[7];
    const float* l1W   = (const float*)d_in[8];
    const float* l1b   = (const float*)d_in[9];
    const float* l2W   = (const float*)d_in[10];
    const float* l2b   = (const float*)d_in[11];
    float* out = (float*)d_out;

    char* w = (char*)d_ws;
    ushort* hbf    = (ushort*)(w);                   // 25,600,000 B
    ushort* zbf    = (ushort*)(w + 25600000);        // 25,600,000 B
    ushort* aggout = (ushort*)(w + 51200000);        // 25,600,000 B (head intermediate)
    int*   row_ptr = (int*)   (w + 76800000);        // 400,004 B (reserve 400,640)
    int*   csr     = (int*)   (w + 77200640);        // 6,400,000 B
    uint*  tmp     = (uint*)  (w + 83600640);        // 6,400,000 B
    int*   hist    = (int*)   (w + 90000640);        // 100,096*4 = 400,384 (reserve 400,640)
    int*   psums   = (int*)   (w + 90401280);        // reserve 2,048
    float* gsum    = (float*) (w + 90403328);        // 128 f
    float* gsq     = gsum + 128;
    float* scale   = gsum + 256;
    float* shift   = gsum + 384;

    const int* src = ei;
    const int* dst = ei + N_EDGES;

    const int GEMM_NB = (N_NODES + 127) / 128;       // 782

    // ---- CSR build (radix partition, zero global atomics) ----
    k_hist<<<NBLK, 256, 0, stream>>>(dst, hist);
    k_scan1<<<SCAN_BLKS, 256, 0, stream>>>(hist, psums);
    k_scan2<<<1, 512, 0, stream>>>(psums);
    k_scan3<<<SCAN_BLKS, 256, 0, stream>>>(hist, psums);
    k_partition<<<NBLK, 256, 0, stream>>>(src, dst, hist, tmp);
    k_bucket_fill<<<NBUK, 256, 0, stream>>>(tmp, hist, row_ptr, csr);

    // ---- x -> bf16 ----
    k_tobf16<<<(N_NODES * D / 4 + 255) / 256, 256, 0, stream>>>(x, hbf);

    // ---- 3 GIN layers ----
    for (int l = 0; l < NLAYERS; ++l) {
        hipMemsetAsync(gsum, 0, 256 * sizeof(float), stream);
        // fused: agg -> z = agg @ W1.T + b1 (bf16) + column stats
        k_agg_gemm<<<NBUK, 256, 0, stream>>>(hbf, row_ptr, csr, W1 + l * D * D, b1 + l * D,
                                             zbf, gsum, gsq);
        k_bnfin<<<1, 128, 0, stream>>>(gsum, gsq, gamma + l * D, beta + l * D, scale, shift);
        // h' = relu( relu(BN(z)) @ W2.T + b2 )
        k_gemm<2, 1><<<GEMM_NB, 256, 0, stream>>>(zbf, W2 + l * D * D, b2 + l * D,
                                                  scale, shift, hbf, N_NODES);
    }

    // ---- head ----
    k_gemm<0, 1><<<GEMM_NB, 256, 0, stream>>>(hbf, l1W, l1b, nullptr, nullptr,
                                              aggout, N_NODES);
    k_head2<<<GEMM_NB, 128, 0, stream>>>(aggout, l2W, l2b, out);
}

// Round 5
// 600.189 us; speedup vs baseline: 1.5849x; 1.5849x over previous
//
#include <hip/hip_runtime.h>
#include <math.h>

#define N_NODES 100000
#define N_EDGES 1600000
#define D 128
#define NCLASS 10
#define NLAYERS 3
#define BN_EPS 1e-5f

#define LDA 136        // padded LDS row stride in bf16 elems
#define BUCKET_SH 7    // 128 nodes per bucket
#define NBUK 782       // ceil(100000/128)
#define NBLK 128       // partition blocks
#define CHUNK 12500    // N_EDGES / NBLK (exact)
#define SCAN_BLKS 391  // (NBUK*NBLK)/256

typedef __attribute__((ext_vector_type(8))) short bf16x8;
typedef __attribute__((ext_vector_type(4))) float f32x4;

__device__ __forceinline__ ushort f2b(float x) {          // RNE fp32 -> bf16
    uint u = __float_as_uint(x);
    return (ushort)((u + 0x7fffu + ((u >> 16) & 1u)) >> 16);
}
__device__ __forceinline__ float b2f(uint u) {            // bf16 bits -> fp32 (exact)
    return __uint_as_float(u << 16);
}
__device__ __forceinline__ uint pack2(float a, float b) {
    return (uint)f2b(a) | ((uint)f2b(b) << 16);
}

// ================= CSR build: radix partition, no global atomics =================
__global__ __launch_bounds__(256) void k_hist(const int* __restrict__ dst,
                                              int* __restrict__ hist) {
    __shared__ int lh[NBUK];
    int t = threadIdx.x, b = blockIdx.x;
    for (int i = t; i < NBUK; i += 256) lh[i] = 0;
    __syncthreads();
    int e0 = b * CHUNK;
    for (int e = e0 + t; e < e0 + CHUNK; e += 256)
        atomicAdd(&lh[dst[e] >> BUCKET_SH], 1);
    __syncthreads();
    for (int i = t; i < NBUK; i += 256) hist[i * NBLK + b] = lh[i];
}

__global__ __launch_bounds__(256) void k_scan1(int* __restrict__ hist, int* __restrict__ psums) {
    __shared__ int sh[256];
    int t = threadIdx.x;
    int i = blockIdx.x * 256 + t;
    int v = hist[i];
    sh[t] = v; __syncthreads();
    for (int off = 1; off < 256; off <<= 1) {
        int a = (t >= off) ? sh[t - off] : 0;
        __syncthreads();
        sh[t] += a;
        __syncthreads();
    }
    hist[i] = sh[t] - v;
    if (t == 255) psums[blockIdx.x] = sh[255];
}

__global__ __launch_bounds__(512) void k_scan2(int* __restrict__ psums) {
    __shared__ int sh[512];
    int t = threadIdx.x;
    int v = (t < SCAN_BLKS) ? psums[t] : 0;
    sh[t] = v; __syncthreads();
    for (int off = 1; off < 512; off <<= 1) {
        int a = (t >= off) ? sh[t - off] : 0;
        __syncthreads();
        sh[t] += a;
        __syncthreads();
    }
    if (t < SCAN_BLKS) psums[t] = sh[t] - v;
}

__global__ __launch_bounds__(256) void k_scan3(int* __restrict__ hist, const int* __restrict__ psums) {
    hist[blockIdx.x * 256 + threadIdx.x] += psums[blockIdx.x];
}

__global__ __launch_bounds__(256) void k_partition(const int* __restrict__ src,
                                                   const int* __restrict__ dst,
                                                   const int* __restrict__ off,
                                                   uint* __restrict__ tmp) {
    __shared__ int lcur[NBUK];
    int t = threadIdx.x, b = blockIdx.x;
    for (int i = t; i < NBUK; i += 256) lcur[i] = off[i * NBLK + b];
    __syncthreads();
    int e0 = b * CHUNK;
    for (int e = e0 + t; e < e0 + CHUNK; e += 256) {
        int d = dst[e];
        int bk = d >> BUCKET_SH;
        int pos = atomicAdd(&lcur[bk], 1);
        tmp[pos] = (uint)src[e] | ((uint)(d & ((1 << BUCKET_SH) - 1)) << 17);
    }
}

__global__ __launch_bounds__(256) void k_bucket_fill(const uint* __restrict__ tmp,
                                                     const int* __restrict__ off,
                                                     int* __restrict__ row_ptr,
                                                     int* __restrict__ csr) {
    __shared__ int hist[128], inc[128], cur[128];
    int b = blockIdx.x, t = threadIdx.x;
    int base = off[b * NBLK];
    int end  = (b + 1 < NBUK) ? off[(b + 1) * NBLK] : N_EDGES;
    int nb = end - base;
    int lo = b << BUCKET_SH;
    const uint* bt = tmp + base;

    if (t < 128) hist[t] = 0;
    __syncthreads();
    for (int i = t; i < nb; i += 256)
        atomicAdd(&hist[bt[i] >> 17], 1);
    __syncthreads();
    if (t < 128) inc[t] = hist[t];
    __syncthreads();
    for (int offs = 1; offs < 128; offs <<= 1) {
        int a = (t < 128 && t >= offs) ? inc[t - offs] : 0;
        __syncthreads();
        if (t < 128) inc[t] += a;
        __syncthreads();
    }
    if (t < 128) {
        int node = lo + t;
        if (node < N_NODES) row_ptr[node] = base + inc[t] - hist[t];
        cur[t] = 0;
    }
    if (b == NBUK - 1 && t == 0) row_ptr[N_NODES] = base + nb;
    __syncthreads();
    for (int i = t; i < nb; i += 256) {
        uint u = bt[i];
        int dl = u >> 17;
        int s = (int)(u & 0x1ffffu);
        int p = atomicAdd(&cur[dl], 1);
        csr[base + (inc[dl] - hist[dl]) + p] = s;
    }
}

// ================= fp32 -> bf16 bulk convert =================
__global__ void k_tobf16(const float* __restrict__ x, ushort* __restrict__ o) {
    int i = blockIdx.x * 256 + threadIdx.x;
    const int n4 = N_NODES * D / 4;
    if (i < n4) {
        float4 v = ((const float4*)x)[i];
        uint2 u;
        u.x = pack2(v.x, v.y);
        u.y = pack2(v.z, v.w);
        ((uint2*)o)[i] = u;
    }
}

// ================= aggregation (bf16 gather, fp32 accum, bf16 out) =================
__global__ __launch_bounds__(256) void k_aggregate(const ushort* __restrict__ hbf,
                                                   const int* __restrict__ row_ptr,
                                                   const int* __restrict__ csr,
                                                   ushort* __restrict__ outbf) {
    int node = blockIdx.x * 4 + (threadIdx.x >> 6);
    int lane = threadIdx.x & 63;
    const uint* hp = (const uint*)hbf;
    uint self = hp[(size_t)node * 64 + lane];
    float ax = b2f(self & 0xffffu), ay = b2f(self >> 16);
    int e0 = row_ptr[node], e1 = row_ptr[node + 1];
    int e = e0;
    for (; e + 7 < e1; e += 8) {
        uint v0 = hp[(size_t)csr[e]     * 64 + lane];
        uint v1 = hp[(size_t)csr[e + 1] * 64 + lane];
        uint v2 = hp[(size_t)csr[e + 2] * 64 + lane];
        uint v3 = hp[(size_t)csr[e + 3] * 64 + lane];
        uint v4 = hp[(size_t)csr[e + 4] * 64 + lane];
        uint v5 = hp[(size_t)csr[e + 5] * 64 + lane];
        uint v6 = hp[(size_t)csr[e + 6] * 64 + lane];
        uint v7 = hp[(size_t)csr[e + 7] * 64 + lane];
        ax += b2f(v0 & 0xffffu); ay += b2f(v0 >> 16);
        ax += b2f(v1 & 0xffffu); ay += b2f(v1 >> 16);
        ax += b2f(v2 & 0xffffu); ay += b2f(v2 >> 16);
        ax += b2f(v3 & 0xffffu); ay += b2f(v3 >> 16);
        ax += b2f(v4 & 0xffffu); ay += b2f(v4 >> 16);
        ax += b2f(v5 & 0xffffu); ay += b2f(v5 >> 16);
        ax += b2f(v6 & 0xffffu); ay += b2f(v6 >> 16);
        ax += b2f(v7 & 0xffffu); ay += b2f(v7 >> 16);
    }
    for (; e < e1; ++e) {
        uint v = hp[(size_t)csr[e] * 64 + lane];
        ax += b2f(v & 0xffffu); ay += b2f(v >> 16);
    }
    ((uint*)outbf)[(size_t)node * 64 + lane] = pack2(ax, ay);
}

// ================= MFMA GEMM =================
// PRE: 0 = copy bf16 A; 2 = relu(a*scale[k]+shift[k]).  POST: 1 = relu.
// STATS: fused column sum/sumsq (fp32 acc+bias, pre-rounding).  bf16 out.
template <int PRE, int POST, int STATS>
__global__ __launch_bounds__(256, 2) void k_gemm(const ushort* __restrict__ inA,
                                                 const float* __restrict__ W,
                                                 const float* __restrict__ bias,
                                                 const float* __restrict__ scale,
                                                 const float* __restrict__ shift,
                                                 ushort* __restrict__ outp,
                                                 float* __restrict__ gsum,
                                                 float* __restrict__ gsq,
                                                 int nrows) {
    __shared__ ushort sA[128 * LDA];
    __shared__ ushort sB[128 * LDA];
    __shared__ float sbias[128];

    int t = threadIdx.x;
    int r0 = blockIdx.x * 128;

    for (int idx = t; idx < 128 * 32; idx += 256) {
        int f = idx >> 5, c4 = (idx & 31) << 2;
        float4 v = *(const float4*)(W + f * 128 + c4);
        ushort4 u;
        u.x = f2b(v.x); u.y = f2b(v.y); u.z = f2b(v.z); u.w = f2b(v.w);
        *(ushort4*)&sB[f * LDA + c4] = u;
    }
    if (t < 128) sbias[t] = bias[t];

    for (int idx = t; idx < 128 * 16; idx += 256) {
        int r = idx >> 4, c8 = (idx & 15) << 3;
        int rr = r0 + r;
        uint4 v = make_uint4(0u, 0u, 0u, 0u);
        if (rr < nrows) v = *(const uint4*)(inA + (size_t)rr * 128 + c8);
        if (PRE == 2) {
            float f0 = b2f(v.x & 0xffffu), f1 = b2f(v.x >> 16);
            float f2 = b2f(v.y & 0xffffu), f3 = b2f(v.y >> 16);
            float f4 = b2f(v.z & 0xffffu), f5 = b2f(v.z >> 16);
            float f6 = b2f(v.w & 0xffffu), f7 = b2f(v.w >> 16);
            float4 sc0 = *(const float4*)(scale + c8);
            float4 sc1 = *(const float4*)(scale + c8 + 4);
            float4 sf0 = *(const float4*)(shift + c8);
            float4 sf1 = *(const float4*)(shift + c8 + 4);
            f0 = fmaxf(fmaf(f0, sc0.x, sf0.x), 0.f);
            f1 = fmaxf(fmaf(f1, sc0.y, sf0.y), 0.f);
            f2 = fmaxf(fmaf(f2, sc0.z, sf0.z), 0.f);
            f3 = fmaxf(fmaf(f3, sc0.w, sf0.w), 0.f);
            f4 = fmaxf(fmaf(f4, sc1.x, sf1.x), 0.f);
            f5 = fmaxf(fmaf(f5, sc1.y, sf1.y), 0.f);
            f6 = fmaxf(fmaf(f6, sc1.z, sf1.z), 0.f);
            f7 = fmaxf(fmaf(f7, sc1.w, sf1.w), 0.f);
            v.x = pack2(f0, f1); v.y = pack2(f2, f3);
            v.z = pack2(f4, f5); v.w = pack2(f6, f7);
        }
        *(uint4*)&sA[r * LDA + c8] = v;
    }
    __syncthreads();

    int lane = t & 63, wid = t >> 6;
    int rl = lane & 15, g = lane >> 4;
    int wr = wid >> 1, wc = wid & 1;

    f32x4 acc[4][4];
#pragma unroll
    for (int i = 0; i < 4; ++i)
#pragma unroll
        for (int j = 0; j < 4; ++j) acc[i][j] = (f32x4){0.f, 0.f, 0.f, 0.f};

#pragma unroll
    for (int ks = 0; ks < 4; ++ks) {
        int koff = ks * 32 + g * 8;
        bf16x8 a[4], b[4];
#pragma unroll
        for (int mi = 0; mi < 4; ++mi)
            a[mi] = *(const bf16x8*)&sA[(wr * 64 + mi * 16 + rl) * LDA + koff];
#pragma unroll
        for (int ni = 0; ni < 4; ++ni)
            b[ni] = *(const bf16x8*)&sB[(wc * 64 + ni * 16 + rl) * LDA + koff];
#pragma unroll
        for (int mi = 0; mi < 4; ++mi)
#pragma unroll
            for (int ni = 0; ni < 4; ++ni)
                acc[mi][ni] = __builtin_amdgcn_mfma_f32_16x16x32_bf16(a[mi], b[ni], acc[mi][ni], 0, 0, 0);
    }

    float bn[4], ssum[4], ssq[4];
#pragma unroll
    for (int ni = 0; ni < 4; ++ni) {
        bn[ni] = sbias[wc * 64 + ni * 16 + rl];
        ssum[ni] = 0.f; ssq[ni] = 0.f;
    }

#pragma unroll
    for (int mi = 0; mi < 4; ++mi) {
        int orow = r0 + wr * 64 + mi * 16 + g * 4;
#pragma unroll
        for (int j = 0; j < 4; ++j) {
            int row = orow + j;
            if (row < nrows) {
#pragma unroll
                for (int ni = 0; ni < 4; ++ni) {
                    int ocol = wc * 64 + ni * 16 + rl;
                    float o = acc[mi][ni][j] + bn[ni];
                    if (STATS) { ssum[ni] += o; ssq[ni] += o * o; }
                    if (POST) o = fmaxf(o, 0.f);
                    outp[(size_t)row * 128 + ocol] = f2b(o);
                }
            }
        }
    }

    if (STATS) {
#pragma unroll
        for (int ni = 0; ni < 4; ++ni) {
            float s = ssum[ni], q = ssq[ni];
            s += __shfl_xor(s, 16, 64); q += __shfl_xor(q, 16, 64);
            s += __shfl_xor(s, 32, 64); q += __shfl_xor(q, 32, 64);
            if (g == 0) {
                int col = wc * 64 + ni * 16 + rl;
                atomicAdd(&gsum[col], s);
                atomicAdd(&gsq[col], q);
            }
        }
    }
}

// ================= BN finalize =================
__global__ void k_bnfin(const float* __restrict__ gsum, const float* __restrict__ gsq,
                        const float* __restrict__ gamma, const float* __restrict__ beta,
                        float* __restrict__ scale, float* __restrict__ shift) {
    int d = threadIdx.x;
    float mu = gsum[d] * (1.f / N_NODES);
    float var = gsq[d] * (1.f / N_NODES) - mu * mu;
    float rstd = rsqrtf(var + BN_EPS);
    float sc = rstd * gamma[d];
    scale[d] = sc;
    shift[d] = beta[d] - mu * sc;
}

// ================= head: out = sigmoid(tin @ lin2_W.T + lin2_b) =================
__global__ __launch_bounds__(128) void k_head2(const ushort* __restrict__ tin,
                                               const float* __restrict__ W2,
                                               const float* __restrict__ b2,
                                               float* __restrict__ out) {
    __shared__ float sh[128 * 130];
    __shared__ float w2s[NCLASS * 128];
    __shared__ float b2s[NCLASS];
    int t = threadIdx.x;
    int r0 = blockIdx.x * 128;

    for (int idx = t; idx < (NCLASS * 128) / 4; idx += 128) {
        float4 v = *(const float4*)(W2 + idx * 4);
        *(float4*)&w2s[idx * 4] = v;
    }
    if (t < NCLASS) b2s[t] = b2[t];

    const uint* tp = (const uint*)tin;
    for (int idx = t; idx < 128 * 64; idx += 128) {
        int r = idx >> 6, c2 = idx & 63;
        int rr = r0 + r;
        uint v = (rr < N_NODES) ? tp[(size_t)rr * 64 + c2] : 0u;
        sh[r * 130 + 2 * c2]     = b2f(v & 0xffffu);
        sh[r * 130 + 2 * c2 + 1] = b2f(v >> 16);
    }
    __syncthreads();

    float acc[NCLASS];
#pragma unroll
    for (int c = 0; c < NCLASS; ++c) acc[c] = 0.f;
    const float* myrow = &sh[t * 130];
#pragma unroll 4
    for (int k = 0; k < 128; ++k) {
        float v = myrow[k];
#pragma unroll
        for (int c = 0; c < NCLASS; ++c)
            acc[c] = fmaf(v, w2s[c * 128 + k], acc[c]);
    }
    int rr = r0 + t;
    if (rr < N_NODES) {
#pragma unroll
        for (int c = 0; c < NCLASS; ++c) {
            float z = acc[c] + b2s[c];
            out[(size_t)rr * NCLASS + c] = 1.f / (1.f + expf(-z));
        }
    }
}

// ================= launcher =================
extern "C" void kernel_launch(void* const* d_in, const int* in_sizes, int n_in,
                              void* d_out, int out_size, void* d_ws, size_t ws_size,
                              hipStream_t stream) {
    const float* x     = (const float*)d_in[0];
    const int*   ei    = (const int*)d_in[1];
    const float* W1    = (const float*)d_in[2];
    const float* b1    = (const float*)d_in[3];
    const float* gamma = (const float*)d_in[4];
    const float* beta  = (const float*)d_in[5];
    const float* W2    = (const float*)d_in[6];
    const float* b2    = (const float*)d_in[7];
    const float* l1W   = (const float*)d_in[8];
    const float* l1b   = (const float*)d_in[9];
    const float* l2W   = (const float*)d_in[10];
    const float* l2b   = (const float*)d_in[11];
    float* out = (float*)d_out;

    char* w = (char*)d_ws;
    ushort* hbf    = (ushort*)(w);                   // 25,600,000 B
    ushort* zbf    = (ushort*)(w + 25600000);        // 25,600,000 B
    ushort* aggout = (ushort*)(w + 51200000);        // 25,600,000 B
    int*   row_ptr = (int*)   (w + 76800000);        // 400,004 B (reserve 400,640)
    int*   csr     = (int*)   (w + 77200640);        // 6,400,000 B
    uint*  tmp     = (uint*)  (w + 83600640);        // 6,400,000 B
    int*   hist    = (int*)   (w + 90000640);        // 400,384 (reserve 400,640)
    int*   psums   = (int*)   (w + 90401280);        // reserve 2,048
    float* gsum    = (float*) (w + 90403328);        // 128 f
    float* gsq     = gsum + 128;
    float* scale   = gsum + 256;
    float* shift   = gsum + 384;

    const int* src = ei;
    const int* dst = ei + N_EDGES;

    const int GEMM_NB = (N_NODES + 127) / 128;       // 782

    // ---- CSR build (radix partition, zero global atomics) ----
    k_hist<<<NBLK, 256, 0, stream>>>(dst, hist);
    k_scan1<<<SCAN_BLKS, 256, 0, stream>>>(hist, psums);
    k_scan2<<<1, 512, 0, stream>>>(psums);
    k_scan3<<<SCAN_BLKS, 256, 0, stream>>>(hist, psums);
    k_partition<<<NBLK, 256, 0, stream>>>(src, dst, hist, tmp);
    k_bucket_fill<<<NBUK, 256, 0, stream>>>(tmp, hist, row_ptr, csr);

    // ---- x -> bf16 ----
    k_tobf16<<<(N_NODES * D / 4 + 255) / 256, 256, 0, stream>>>(x, hbf);

    // ---- 3 GIN layers ----
    for (int l = 0; l < NLAYERS; ++l) {
        k_aggregate<<<N_NODES / 4, 256, 0, stream>>>(hbf, row_ptr, csr, aggout);
        hipMemsetAsync(gsum, 0, 256 * sizeof(float), stream);
        // z = (h+agg) @ W1.T + b1  (bf16 out) + fused column stats
        k_gemm<0, 0, 1><<<GEMM_NB, 256, 0, stream>>>(aggout, W1 + l * D * D, b1 + l * D,
                                                     nullptr, nullptr, zbf, gsum, gsq, N_NODES);
        k_bnfin<<<1, 128, 0, stream>>>(gsum, gsq, gamma + l * D, beta + l * D, scale, shift);
        // h' = relu( relu(BN(z)) @ W2.T + b2 )
        k_gemm<2, 1, 0><<<GEMM_NB, 256, 0, stream>>>(zbf, W2 + l * D * D, b2 + l * D,
                                                     scale, shift, hbf, nullptr, nullptr, N_NODES);
    }

    // ---- head ----
    k_gemm<0, 1, 0><<<GEMM_NB, 256, 0, stream>>>(hbf, l1W, l1b, nullptr, nullptr,
                                                 aggout, nullptr, nullptr, N_NODES);
    k_head2<<<GEMM_NB, 128, 0, stream>>>(aggout, l2W, l2b, out);
}

// Round 6
// 497.252 us; speedup vs baseline: 1.9129x; 1.2070x over previous
//
#include <hip/hip_runtime.h>
#include <math.h>

#define N_NODES 100000
#define N_EDGES 1600000
#define D 128
#define NCLASS 10
#define NLAYERS 3
#define BN_EPS 1e-5f

#define LDA 136        // padded LDS row stride in bf16 elems
#define BUCKET_SH 7    // 128 nodes per bucket
#define NBUK 782       // ceil(100000/128)
#define NBLK 256       // partition blocks (== scan chunk size -> psums[i] = bucket i base)
#define CHUNK 6250     // N_EDGES / NBLK (exact)
#define SCAN_BLKS NBUK // hist rows = buckets

typedef __attribute__((ext_vector_type(8))) short bf16x8;
typedef __attribute__((ext_vector_type(4))) float f32x4;

__device__ __forceinline__ ushort f2b(float x) {          // RNE fp32 -> bf16
    uint u = __float_as_uint(x);
    return (ushort)((u + 0x7fffu + ((u >> 16) & 1u)) >> 16);
}
__device__ __forceinline__ float b2f(uint u) {            // bf16 bits -> fp32 (exact)
    return __uint_as_float(u << 16);
}
__device__ __forceinline__ uint pack2(float a, float b) {
    return (uint)f2b(a) | ((uint)f2b(b) << 16);
}

// ================= CSR build: radix partition, no global atomics =================
// A: per-block histogram over buckets -> hist[buk*NBLK + blk]
__global__ __launch_bounds__(256) void k_hist(const int* __restrict__ dst,
                                              int* __restrict__ hist) {
    __shared__ int lh[NBUK];
    int t = threadIdx.x, b = blockIdx.x;
    for (int i = t; i < NBUK; i += 256) lh[i] = 0;
    __syncthreads();
    int e0 = b * CHUNK;
    for (int e = e0 + t; e < e0 + CHUNK; e += 256)
        atomicAdd(&lh[dst[e] >> BUCKET_SH], 1);
    __syncthreads();
    for (int i = t; i < NBUK; i += 256) hist[i * NBLK + b] = lh[i];
}

// B1: within-bucket-row exclusive scan (256 entries = one bucket row), row totals -> psums
__global__ __launch_bounds__(256) void k_scan1(int* __restrict__ hist, int* __restrict__ psums) {
    __shared__ int sh[256];
    int t = threadIdx.x;
    int i = blockIdx.x * 256 + t;
    int v = hist[i];
    sh[t] = v; __syncthreads();
    for (int off = 1; off < 256; off <<= 1) {
        int a = (t >= off) ? sh[t - off] : 0;
        __syncthreads();
        sh[t] += a;
        __syncthreads();
    }
    hist[i] = sh[t] - v;
    if (t == 255) psums[blockIdx.x] = sh[255];
}

// B2: exclusive scan of the 782 bucket totals -> psums[b] = global base of bucket b
__global__ __launch_bounds__(1024) void k_scan2(int* __restrict__ psums) {
    __shared__ int sh[1024];
    int t = threadIdx.x;
    int v = (t < SCAN_BLKS) ? psums[t] : 0;
    sh[t] = v; __syncthreads();
    for (int off = 1; off < 1024; off <<= 1) {
        int a = (t >= off) ? sh[t - off] : 0;
        __syncthreads();
        sh[t] += a;
        __syncthreads();
    }
    if (t < SCAN_BLKS) psums[t] = sh[t] - v;
}

// C: planned scatter via LDS cursors (packed src | d_local<<17)
__global__ __launch_bounds__(256) void k_partition(const int* __restrict__ src,
                                                   const int* __restrict__ dst,
                                                   const int* __restrict__ hist,
                                                   const int* __restrict__ psums,
                                                   uint* __restrict__ tmp) {
    __shared__ int lcur[NBUK];
    int t = threadIdx.x, b = blockIdx.x;
    for (int i = t; i < NBUK; i += 256) lcur[i] = hist[i * NBLK + b] + psums[i];
    __syncthreads();
    int e0 = b * CHUNK;
    for (int e = e0 + t; e < e0 + CHUNK; e += 256) {
        int d = dst[e];
        int bk = d >> BUCKET_SH;
        int pos = atomicAdd(&lcur[bk], 1);
        tmp[pos] = (uint)src[e] | ((uint)(d & ((1 << BUCKET_SH) - 1)) << 17);
    }
}

// D: per-bucket LDS histogram + scan -> row_ptr + csr fill (LDS cursors only)
__global__ __launch_bounds__(256) void k_bucket_fill(const uint* __restrict__ tmp,
                                                     const int* __restrict__ psums,
                                                     int* __restrict__ row_ptr,
                                                     int* __restrict__ csr) {
    __shared__ int hist[128], inc[128], cur[128];
    int b = blockIdx.x, t = threadIdx.x;
    int base = psums[b];
    int end  = (b + 1 < NBUK) ? psums[b + 1] : N_EDGES;
    int nb = end - base;
    int lo = b << BUCKET_SH;
    const uint* bt = tmp + base;

    if (t < 128) hist[t] = 0;
    __syncthreads();
    for (int i = t; i < nb; i += 256)
        atomicAdd(&hist[bt[i] >> 17], 1);
    __syncthreads();
    if (t < 128) inc[t] = hist[t];
    __syncthreads();
    for (int offs = 1; offs < 128; offs <<= 1) {
        int a = (t < 128 && t >= offs) ? inc[t - offs] : 0;
        __syncthreads();
        if (t < 128) inc[t] += a;
        __syncthreads();
    }
    if (t < 128) {
        int node = lo + t;
        if (node < N_NODES) row_ptr[node] = base + inc[t] - hist[t];
        cur[t] = 0;
    }
    if (b == NBUK - 1 && t == 0) row_ptr[N_NODES] = base + nb;
    __syncthreads();
    for (int i = t; i < nb; i += 256) {
        uint u = bt[i];
        int dl = u >> 17;
        int s = (int)(u & 0x1ffffu);
        int p = atomicAdd(&cur[dl], 1);
        csr[base + (inc[dl] - hist[dl]) + p] = s;
    }
}

// ================= fp32 -> bf16 bulk convert =================
__global__ void k_tobf16(const float* __restrict__ x, ushort* __restrict__ o) {
    int i = blockIdx.x * 256 + threadIdx.x;
    const int n4 = N_NODES * D / 4;
    if (i < n4) {
        float4 v = ((const float4*)x)[i];
        uint2 u;
        u.x = pack2(v.x, v.y);
        u.y = pack2(v.z, v.w);
        ((uint2*)o)[i] = u;
    }
}

// ================= aggregation (bf16 gather, fp32 accum, bf16 out) =================
__global__ __launch_bounds__(256) void k_aggregate(const ushort* __restrict__ hbf,
                                                   const int* __restrict__ row_ptr,
                                                   const int* __restrict__ csr,
                                                   ushort* __restrict__ outbf) {
    int node = blockIdx.x * 4 + (threadIdx.x >> 6);
    int lane = threadIdx.x & 63;
    const uint* hp = (const uint*)hbf;
    uint self = hp[(size_t)node * 64 + lane];
    float ax = b2f(self & 0xffffu), ay = b2f(self >> 16);
    int e0 = row_ptr[node], e1 = row_ptr[node + 1];
    int e = e0;
    for (; e + 7 < e1; e += 8) {
        uint v0 = hp[(size_t)csr[e]     * 64 + lane];
        uint v1 = hp[(size_t)csr[e + 1] * 64 + lane];
        uint v2 = hp[(size_t)csr[e + 2] * 64 + lane];
        uint v3 = hp[(size_t)csr[e + 3] * 64 + lane];
        uint v4 = hp[(size_t)csr[e + 4] * 64 + lane];
        uint v5 = hp[(size_t)csr[e + 5] * 64 + lane];
        uint v6 = hp[(size_t)csr[e + 6] * 64 + lane];
        uint v7 = hp[(size_t)csr[e + 7] * 64 + lane];
        ax += b2f(v0 & 0xffffu); ay += b2f(v0 >> 16);
        ax += b2f(v1 & 0xffffu); ay += b2f(v1 >> 16);
        ax += b2f(v2 & 0xffffu); ay += b2f(v2 >> 16);
        ax += b2f(v3 & 0xffffu); ay += b2f(v3 >> 16);
        ax += b2f(v4 & 0xffffu); ay += b2f(v4 >> 16);
        ax += b2f(v5 & 0xffffu); ay += b2f(v5 >> 16);
        ax += b2f(v6 & 0xffffu); ay += b2f(v6 >> 16);
        ax += b2f(v7 & 0xffffu); ay += b2f(v7 >> 16);
    }
    for (; e < e1; ++e) {
        uint v = hp[(size_t)csr[e] * 64 + lane];
        ax += b2f(v & 0xffffu); ay += b2f(v >> 16);
    }
    __builtin_nontemporal_store(pack2(ax, ay), (uint*)outbf + (size_t)node * 64 + lane);
}

// ================= MFMA GEMM =================
// PRE: 0 = copy bf16 A; 2 = relu(a*scale[k]+shift[k]).  POST: 1 = relu.
// STATS: fused column sum/sumsq (fp32, pre-rounding), LDS-reduced, 128 atomics/block/array.
template <int PRE, int POST, int STATS>
__global__ __launch_bounds__(256, 2) void k_gemm(const ushort* __restrict__ inA,
                                                 const float* __restrict__ W,
                                                 const float* __restrict__ bias,
                                                 const float* __restrict__ scale,
                                                 const float* __restrict__ shift,
                                                 ushort* __restrict__ outp,
                                                 float* __restrict__ gsum,
                                                 float* __restrict__ gsq,
                                                 int nrows) {
    __shared__ ushort sA[128 * LDA];
    __shared__ ushort sB[128 * LDA];
    __shared__ float sbias[128];
    __shared__ float lsum[128], lsq[128];

    int t = threadIdx.x;
    int r0 = blockIdx.x * 128;

    for (int idx = t; idx < 128 * 32; idx += 256) {
        int f = idx >> 5, c4 = (idx & 31) << 2;
        float4 v = *(const float4*)(W + f * 128 + c4);
        ushort4 u;
        u.x = f2b(v.x); u.y = f2b(v.y); u.z = f2b(v.z); u.w = f2b(v.w);
        *(ushort4*)&sB[f * LDA + c4] = u;
    }
    if (t < 128) {
        sbias[t] = bias[t];
        lsum[t] = 0.f; lsq[t] = 0.f;
    }

    for (int idx = t; idx < 128 * 16; idx += 256) {
        int r = idx >> 4, c8 = (idx & 15) << 3;
        int rr = r0 + r;
        uint4 v = make_uint4(0u, 0u, 0u, 0u);
        if (rr < nrows) v = *(const uint4*)(inA + (size_t)rr * 128 + c8);
        if (PRE == 2) {
            float f0 = b2f(v.x & 0xffffu), f1 = b2f(v.x >> 16);
            float f2 = b2f(v.y & 0xffffu), f3 = b2f(v.y >> 16);
            float f4 = b2f(v.z & 0xffffu), f5 = b2f(v.z >> 16);
            float f6 = b2f(v.w & 0xffffu), f7 = b2f(v.w >> 16);
            float4 sc0 = *(const float4*)(scale + c8);
            float4 sc1 = *(const float4*)(scale + c8 + 4);
            float4 sf0 = *(const float4*)(shift + c8);
            float4 sf1 = *(const float4*)(shift + c8 + 4);
            f0 = fmaxf(fmaf(f0, sc0.x, sf0.x), 0.f);
            f1 = fmaxf(fmaf(f1, sc0.y, sf0.y), 0.f);
            f2 = fmaxf(fmaf(f2, sc0.z, sf0.z), 0.f);
            f3 = fmaxf(fmaf(f3, sc0.w, sf0.w), 0.f);
            f4 = fmaxf(fmaf(f4, sc1.x, sf1.x), 0.f);
            f5 = fmaxf(fmaf(f5, sc1.y, sf1.y), 0.f);
            f6 = fmaxf(fmaf(f6, sc1.z, sf1.z), 0.f);
            f7 = fmaxf(fmaf(f7, sc1.w, sf1.w), 0.f);
            v.x = pack2(f0, f1); v.y = pack2(f2, f3);
            v.z = pack2(f4, f5); v.w = pack2(f6, f7);
        }
        *(uint4*)&sA[r * LDA + c8] = v;
    }
    __syncthreads();

    int lane = t & 63, wid = t >> 6;
    int rl = lane & 15, g = lane >> 4;
    int wr = wid >> 1, wc = wid & 1;

    f32x4 acc[4][4];
#pragma unroll
    for (int i = 0; i < 4; ++i)
#pragma unroll
        for (int j = 0; j < 4; ++j) acc[i][j] = (f32x4){0.f, 0.f, 0.f, 0.f};

#pragma unroll
    for (int ks = 0; ks < 4; ++ks) {
        int koff = ks * 32 + g * 8;
        bf16x8 a[4], b[4];
#pragma unroll
        for (int mi = 0; mi < 4; ++mi)
            a[mi] = *(const bf16x8*)&sA[(wr * 64 + mi * 16 + rl) * LDA + koff];
#pragma unroll
        for (int ni = 0; ni < 4; ++ni)
            b[ni] = *(const bf16x8*)&sB[(wc * 64 + ni * 16 + rl) * LDA + koff];
#pragma unroll
        for (int mi = 0; mi < 4; ++mi)
#pragma unroll
            for (int ni = 0; ni < 4; ++ni)
                acc[mi][ni] = __builtin_amdgcn_mfma_f32_16x16x32_bf16(a[mi], b[ni], acc[mi][ni], 0, 0, 0);
    }

    float bn[4], ssum[4], ssq[4];
#pragma unroll
    for (int ni = 0; ni < 4; ++ni) {
        bn[ni] = sbias[wc * 64 + ni * 16 + rl];
        ssum[ni] = 0.f; ssq[ni] = 0.f;
    }

#pragma unroll
    for (int mi = 0; mi < 4; ++mi) {
        int orow = r0 + wr * 64 + mi * 16 + g * 4;
#pragma unroll
        for (int j = 0; j < 4; ++j) {
            int row = orow + j;
            if (row < nrows) {
#pragma unroll
                for (int ni = 0; ni < 4; ++ni) {
                    int ocol = wc * 64 + ni * 16 + rl;
                    float o = acc[mi][ni][j] + bn[ni];
                    if (STATS) { ssum[ni] += o; ssq[ni] += o * o; }
                    if (POST) o = fmaxf(o, 0.f);
                    outp[(size_t)row * 128 + ocol] = f2b(o);
                }
            }
        }
    }

    if (STATS) {
#pragma unroll
        for (int ni = 0; ni < 4; ++ni) {
            float s = ssum[ni], q = ssq[ni];
            s += __shfl_xor(s, 16, 64); q += __shfl_xor(q, 16, 64);
            s += __shfl_xor(s, 32, 64); q += __shfl_xor(q, 32, 64);
            if (g == 0) {
                int col = wc * 64 + ni * 16 + rl;
                atomicAdd(&lsum[col], s);
                atomicAdd(&lsq[col], q);
            }
        }
        __syncthreads();
        if (t < 128) {
            atomicAdd(&gsum[t], lsum[t]);
            atomicAdd(&gsq[t], lsq[t]);
        }
    }
}

// ================= BN finalize (+ self-reset of accumulators) =================
__global__ void k_bnfin(float* __restrict__ gsum, float* __restrict__ gsq,
                        const float* __restrict__ gamma, const float* __restrict__ beta,
                        float* __restrict__ scale, float* __restrict__ shift) {
    int d = threadIdx.x;
    float s = gsum[d], q = gsq[d];
    float mu = s * (1.f / N_NODES);
    float var = q * (1.f / N_NODES) - mu * mu;
    float rstd = rsqrtf(var + BN_EPS);
    float sc = rstd * gamma[d];
    scale[d] = sc;
    shift[d] = beta[d] - mu * sc;
    gsum[d] = 0.f;     // ready for next layer / next call
    gsq[d] = 0.f;
}

// ================= fused head: out = sigmoid(relu(h@l1W.T+l1b) @ l2W.T + l2b) ========
__global__ __launch_bounds__(256, 2) void k_head(const ushort* __restrict__ hbf,
                                                 const float* __restrict__ W1,
                                                 const float* __restrict__ b1f,
                                                 const float* __restrict__ W2,
                                                 const float* __restrict__ b2f_,
                                                 float* __restrict__ out) {
    __shared__ ushort sA[128 * LDA];          // h tile, later reused as z^T tile
    __shared__ ushort sB[128 * LDA];          // W1 bf16
    __shared__ float sbias[128];
    __shared__ float w2s[NCLASS * 128];
    __shared__ float b2s[NCLASS];

    int t = threadIdx.x;
    int r0 = blockIdx.x * 128;

    for (int idx = t; idx < 128 * 32; idx += 256) {
        int f = idx >> 5, c4 = (idx & 31) << 2;
        float4 v = *(const float4*)(W1 + f * 128 + c4);
        ushort4 u;
        u.x = f2b(v.x); u.y = f2b(v.y); u.z = f2b(v.z); u.w = f2b(v.w);
        *(ushort4*)&sB[f * LDA + c4] = u;
    }
    if (t < 128) sbias[t] = b1f[t];
    for (int idx = t; idx < (NCLASS * 128) / 4; idx += 256)
        *(float4*)&w2s[idx * 4] = *(const float4*)(W2 + idx * 4);
    if (t < NCLASS) b2s[t] = b2f_[t];

    for (int idx = t; idx < 128 * 16; idx += 256) {
        int r = idx >> 4, c8 = (idx & 15) << 3;
        int rr = r0 + r;
        uint4 v = make_uint4(0u, 0u, 0u, 0u);
        if (rr < N_NODES) v = *(const uint4*)(hbf + (size_t)rr * 128 + c8);
        *(uint4*)&sA[r * LDA + c8] = v;
    }
    __syncthreads();

    int lane = t & 63, wid = t >> 6;
    int rl = lane & 15, g = lane >> 4;
    int wr = wid >> 1, wc = wid & 1;

    f32x4 acc[4][4];
#pragma unroll
    for (int i = 0; i < 4; ++i)
#pragma unroll
        for (int j = 0; j < 4; ++j) acc[i][j] = (f32x4){0.f, 0.f, 0.f, 0.f};

#pragma unroll
    for (int ks = 0; ks < 4; ++ks) {
        int koff = ks * 32 + g * 8;
        bf16x8 a[4], b[4];
#pragma unroll
        for (int mi = 0; mi < 4; ++mi)
            a[mi] = *(const bf16x8*)&sA[(wr * 64 + mi * 16 + rl) * LDA + koff];
#pragma unroll
        for (int ni = 0; ni < 4; ++ni)
            b[ni] = *(const bf16x8*)&sB[(wc * 64 + ni * 16 + rl) * LDA + koff];
#pragma unroll
        for (int mi = 0; mi < 4; ++mi)
#pragma unroll
            for (int ni = 0; ni < 4; ++ni)
                acc[mi][ni] = __builtin_amdgcn_mfma_f32_16x16x32_bf16(a[mi], b[ni], acc[mi][ni], 0, 0, 0);
    }

    __syncthreads();   // all waves done reading sA -> safe to overwrite with z^T

    float bn[4];
#pragma unroll
    for (int ni = 0; ni < 4; ++ni) bn[ni] = sbias[wc * 64 + ni * 16 + rl];
#pragma unroll
    for (int mi = 0; mi < 4; ++mi) {
        int rowl = wr * 64 + mi * 16 + g * 4;
#pragma unroll
        for (int j = 0; j < 4; ++j) {
#pragma unroll
            for (int ni = 0; ni < 4; ++ni) {
                int ocol = wc * 64 + ni * 16 + rl;
                float o = fmaxf(acc[mi][ni][j] + bn[ni], 0.f);
                sA[ocol * LDA + rowl + j] = f2b(o);   // z^T: [col][row]
            }
        }
    }
    __syncthreads();

    // lin2 + sigmoid: row = t&127, class-half = t>>7
    int row = t & 127, ch = t >> 7;
    float acc2[5] = {0.f, 0.f, 0.f, 0.f, 0.f};
    const float* w2p = &w2s[ch * 5 * 128];
#pragma unroll 4
    for (int k = 0; k < 128; ++k) {
        float v = b2f(sA[k * LDA + row]);
#pragma unroll
        for (int c = 0; c < 5; ++c)
            acc2[c] = fmaf(v, w2p[c * 128 + k], acc2[c]);
    }
    int rr = r0 + row;
    if (rr < N_NODES) {
#pragma unroll
        for (int c = 0; c < 5; ++c) {
            float z = acc2[c] + b2s[ch * 5 + c];
            out[(size_t)rr * NCLASS + ch * 5 + c] = 1.f / (1.f + expf(-z));
        }
    }
}

// ================= launcher =================
extern "C" void kernel_launch(void* const* d_in, const int* in_sizes, int n_in,
                              void* d_out, int out_size, void* d_ws, size_t ws_size,
                              hipStream_t stream) {
    const float* x     = (const float*)d_in[0];
    const int*   ei    = (const int*)d_in[1];
    const float* W1    = (const float*)d_in[2];
    const float* b1    = (const float*)d_in[3];
    const float* gamma = (const float*)d_in[4];
    const float* beta  = (const float*)d_in[5];
    const float* W2    = (const float*)d_in[6];
    const float* b2    = (const float*)d_in[7];
    const float* l1W   = (const float*)d_in[8];
    const float* l1b   = (const float*)d_in[9];
    const float* l2W   = (const float*)d_in[10];
    const float* l2b   = (const float*)d_in[11];
    float* out = (float*)d_out;

    char* w = (char*)d_ws;
    ushort* hbf    = (ushort*)(w);                   // 25,600,000 B
    ushort* zbf    = (ushort*)(w + 25600000);        // 25,600,000 B
    ushort* aggout = (ushort*)(w + 51200000);        // 25,600,000 B
    int*   row_ptr = (int*)   (w + 76800000);        // 400,004 B (reserve 400,640)
    int*   csr     = (int*)   (w + 77200640);        // 6,400,000 B
    uint*  tmp     = (uint*)  (w + 83600640);        // 6,400,000 B
    int*   hist    = (int*)   (w + 90000640);        // 782*256*4 = 800,768 (reserve 801,280)
    int*   psums   = (int*)   (w + 90801920);        // reserve 4,096
    float* gsum    = (float*) (w + 90806016);        // 512 floats
    float* gsq     = gsum + 128;
    float* scale   = gsum + 256;
    float* shift   = gsum + 384;

    const int* src = ei;
    const int* dst = ei + N_EDGES;

    const int GEMM_NB = (N_NODES + 127) / 128;       // 782

    // gsum/gsq init (covers first-call 0xAA poison; bnfin self-resets thereafter)
    hipMemsetAsync(gsum, 0, 256 * sizeof(float), stream);

    // ---- CSR build (radix partition, zero global atomics) ----
    k_hist<<<NBLK, 256, 0, stream>>>(dst, hist);
    k_scan1<<<SCAN_BLKS, 256, 0, stream>>>(hist, psums);
    k_scan2<<<1, 1024, 0, stream>>>(psums);
    k_partition<<<NBLK, 256, 0, stream>>>(src, dst, hist, psums, tmp);
    k_bucket_fill<<<NBUK, 256, 0, stream>>>(tmp, psums, row_ptr, csr);

    // ---- x -> bf16 ----
    k_tobf16<<<(N_NODES * D / 4 + 255) / 256, 256, 0, stream>>>(x, hbf);

    // ---- 3 GIN layers ----
    for (int l = 0; l < NLAYERS; ++l) {
        k_aggregate<<<N_NODES / 4, 256, 0, stream>>>(hbf, row_ptr, csr, aggout);
        // z = (h+agg) @ W1.T + b1  (bf16 out) + fused column stats
        k_gemm<0, 0, 1><<<GEMM_NB, 256, 0, stream>>>(aggout, W1 + l * D * D, b1 + l * D,
                                                     nullptr, nullptr, zbf, gsum, gsq, N_NODES);
        k_bnfin<<<1, 128, 0, stream>>>(gsum, gsq, gamma + l * D, beta + l * D, scale, shift);
        // h' = relu( relu(BN(z)) @ W2.T + b2 )
        k_gemm<2, 1, 0><<<GEMM_NB, 256, 0, stream>>>(zbf, W2 + l * D * D, b2 + l * D,
                                                     scale, shift, hbf, nullptr, nullptr, N_NODES);
    }

    // ---- fused head ----
    k_head<<<GEMM_NB, 256, 0, stream>>>(hbf, l1W, l1b, l2W, l2b, out);
}